// Round 19
// baseline (81.012 us; speedup 1.0000x reference)
//
#include <hip/hip_runtime.h>
#include <hip/hip_bf16.h>

// SoftModule fused forward, MI355X gfx950 — v19.
// Discriminating experiment: v13 code verbatim, but 2 INDEPENDENT waves per
// 128-thread WG (no barriers; disjoint per-wave LDS slices of 15232 B each,
// using the v16-verified pm/ring overlay). If the ~8-WG/CU residency cap is
// real, 5 WG/CU x 2 waves = 10 waves vs 7 -> faster; if waves are capped,
// neutral. Grid 2048, rows: blockIdx*32 + wave*16.

using f32x4 = __attribute__((ext_vector_type(4))) float;
using h16x4 = __attribute__((ext_vector_type(4))) _Float16;
using h16x8 = __attribute__((ext_vector_type(8))) _Float16;
using u32x4 = __attribute__((ext_vector_type(4))) unsigned int;
using u32x2 = __attribute__((ext_vector_type(2))) unsigned int;

#define MFMA16(a, b, c) __builtin_amdgcn_mfma_f32_16x16x16f16((a), (b), (c), 0, 0, 0)

__device__ __forceinline__ short h_bits(float f) {
  _Float16 h = (_Float16)f;
  return __builtin_bit_cast(short, h);
}

__device__ __forceinline__ void dma16(const void* g, char* l) {
  __builtin_amdgcn_global_load_lds(
      (const __attribute__((address_space(1))) unsigned int*)g,
      (__attribute__((address_space(3))) unsigned int*)l, 16, 0, 0);
}

// ---------------- weight convert (v9, verified) -----------------------------
__global__ void sm_convert_v19(
    const float* __restrict__ Ws1, const float* __restrict__ Ws2, const float* __restrict__ Wt,
    const float* __restrict__ Wa0, const float* __restrict__ Wa1, const float* __restrict__ Wc0,
    const float* __restrict__ We0, const float* __restrict__ We1, const float* __restrict__ We2,
    const float* __restrict__ bs1, const float* __restrict__ bs2, const float* __restrict__ bt,
    const float* __restrict__ ba0, const float* __restrict__ ba1, const float* __restrict__ bc0,
    const float* __restrict__ be0, const float* __restrict__ be1, const float* __restrict__ be2,
    short* __restrict__ wsh, float* __restrict__ biasf) {
  int d = blockIdx.x * 256 + threadIdx.x;
  if (d < 64512) {
    float v;
    if (d < 32768) {             // Bp1 (v9 bijection)
      int kk   = d & 3;
      int ntip = (d >> 2) & 1;
      int p    = (d >> 3) & 15;
      int q    = (d >> 7) & 3;
      int pair = (d >> 9) & 1;
      int kb2  = (d >> 10) & 1;
      int c    = d >> 11;
      int k = c * 32 + kb2 * 16 + q * 4 + kk;
      int o = pair * 32 + ntip * 16 + p;
      v = Ws1[k * 64 + o];
    }
    else if (d < 36864) { int r = d - 32768, o = r >> 6, k = r & 63;   v = Ws2[k * 64 + o]; }
    else if (d < 45056) {        // WtP
      int r = d - 36864;
      int kk   = r & 3;
      int ntip = (r >> 2) & 1;
      int p    = (r >> 3) & 15;
      int q    = (r >> 7) & 3;
      int pair = (r >> 9) & 1;
      int kb2  = (r >> 10) & 1;
      int c    = r >> 11;
      int k = c * 32 + kb2 * 16 + q * 4 + kk;
      int o = pair * 32 + ntip * 16 + p;
      v = Wt[k * 64 + o];
    }
    else if (d < 46080) { int r = d - 45056, o = r >> 6, k = r & 63;   v = Wa0[k * 16 + o]; }
    else if (d < 47104) { int r = d - 46080, o = r >> 6, k = r & 63;   v = Wa1[k * 16 + o]; }
    else if (d < 48128) { int r = d - 47104, o = r >> 4, k = r & 15;   v = Wc0[k * 64 + o]; }
    else if (d < 56320) { int r = d - 48128, n = r >> 11, o = (r >> 6) & 31, i = r & 63; v = We0[n * 2048 + i * 32 + o]; }
    else if (d < 60416) { int r = d - 56320, n = r >> 10, o = (r >> 5) & 31, i = r & 31; v = We1[n * 1024 + i * 32 + o]; }
    else                { int r = d - 60416, n = r >> 10, o = (r >> 5) & 31, i = r & 31; v = We2[n * 1024 + i * 32 + o]; }
    wsh[d] = h_bits(v);
  } else if (d < 65184) {
    int r = d - 64512;
    float v;
    if      (r < 64)  v = bs1[r];
    else if (r < 128) v = bs2[r - 64];
    else if (r < 192) v = bt[r - 128];
    else if (r < 208) v = ba0[r - 192];
    else if (r < 224) v = ba1[r - 208];
    else if (r < 288) v = bc0[r - 224];
    else if (r < 416) v = be0[r - 288];
    else if (r < 544) v = be1[r - 416];
    else              v = be2[r - 544];
    biasf[r] = v;
  }
}

// ---------------- fused forward: 2 independent waves per WG -----------------
__global__ __launch_bounds__(128) void sm_fused_v19(
    const float* __restrict__ obs, const float* __restrict__ task,
    const short* __restrict__ wsh, const float* __restrict__ biasf,
    float* __restrict__ out) {
  const int wave = threadIdx.x >> 6;
  const int lane = threadIdx.x & 63;
  const int q    = lane >> 4;
  const int p    = lane & 15;
  const int rowblk = blockIdx.x * 32 + wave * 16;

  // Two disjoint per-wave slices of 15232 B (v13 layout + v16 overlay):
  // x[16][136] @0 (2176) | a[16][48] @2176 (768) |
  // ring[2][6144] @2944 (12288; dead after T) | pm[4][16][80] @2944 overlay.
  __shared__ __align__(16) char lds[30464];
  char* wb     = lds + wave * 15232;
  char* x_lds  = wb;
  char* a_lds  = wb + 2176;
  char* ring   = wb + 2944;
  char* pm_lds = wb + 2944;

  const short* Bp1  = wsh;
  const short* Ws2T = wsh + 32768;
  const short* WtP  = wsh + 36864;
  const short* Wa0T = wsh + 45056;
  const short* Wa1T = wsh + 46080;
  const short* Wc0T = wsh + 47104;
  const short* We0T = wsh + 48128;
  const short* We1T = wsh + 56320;
  const short* We2T = wsh + 60416;
  const float* bs1 = biasf;        const float* bs2 = biasf + 64;
  const float* bt  = biasf + 128;  const float* ba0 = biasf + 192;
  const float* ba1 = biasf + 208;  const float* bc0 = biasf + 224;
  const float* be0 = biasf + 288;  const float* be1 = biasf + 416;
  const float* be2 = biasf + 544;

  const f32x4 z4 = {0.f, 0.f, 0.f, 0.f};

  auto stx  = [&](int row, int col, float v) { *(short*)(x_lds + row * 136 + col * 2) = h_bits(v); };
  auto ldx4 = [&](int row, int k0) -> h16x4 { return *(const h16x4*)(x_lds + row * 136 + k0 * 2); };
  auto ldb  = [&](const short* W, int off) -> h16x4 { return *(const h16x4*)(W + off); };
  auto cvtA = [&](const u32x4& u) -> h16x4 {
    float4 v = __builtin_bit_cast(float4, u);
    h16x4 a;
    a[0] = (_Float16)v.x; a[1] = (_Float16)v.y;
    a[2] = (_Float16)v.z; a[3] = (_Float16)v.w;
    return a;
  };
  auto lo2 = [&](const u32x4& u) -> h16x4 { return __builtin_bit_cast(h16x4, (u32x2){u[0], u[1]}); };
  auto hi2 = [&](const u32x4& u) -> h16x4 { return __builtin_bit_cast(h16x4, (u32x2){u[2], u[3]}); };

  auto stageA = [&](const float* base, int rowlen, int k0, int buf) {
#pragma unroll
    for (int j = 0; j < 2; ++j) {
      int f = j * 64 + lane;
      int row = f >> 3;
      int cl = (f & 7) ^ (row & 7);
      dma16(base + (size_t)(rowblk + row) * rowlen + k0 + cl * 4,
            ring + buf * 6144 + j * 1024);
    }
  };
  auto stageB = [&](const short* bsrc, int c, int buf) {
#pragma unroll
    for (int j = 0; j < 4; ++j)
      dma16((const char*)bsrc + c * 4096 + (j * 64 + lane) * 16,
            ring + buf * 6144 + 2048 + j * 1024);
  };
  auto lda_ = [&](int buf, int kb2) -> u32x4 {
    return *(const u32x4*)(ring + buf * 6144 + p * 128 +
                           (((kb2 * 4 + q) ^ (p & 7)) * 16));
  };
  auto ldbs = [&](int buf, int kb2, int pair) -> u32x4 {
    return *(const u32x4*)(ring + buf * 6144 + 2048 + kb2 * 2048 + pair * 1024 + lane * 16);
  };

  // ---- S1: K=512 = 16 chunks of 32; counted vmcnt, NO barriers ----
  f32x4 accX[4] = {z4, z4, z4, z4};
  {
    stageA(obs, 512, 0, 0); stageB(Bp1, 0, 0);      // 6 DMAs, chunk 0
    for (int c = 0; c < 16; ++c) {
      if (c + 1 < 16) {
        stageA(obs, 512, (c + 1) * 32, (c + 1) & 1);
        stageB(Bp1, c + 1, (c + 1) & 1);
        __builtin_amdgcn_sched_barrier(0);
        asm volatile("s_waitcnt vmcnt(6)" ::: "memory");  // retires chunk c
      } else {
        asm volatile("s_waitcnt vmcnt(0)" ::: "memory");
      }
      __builtin_amdgcn_sched_barrier(0);
      const int buf = c & 1;
#pragma unroll
      for (int kb2 = 0; kb2 < 2; ++kb2) {
        h16x4 a = cvtA(lda_(buf, kb2));
        u32x4 B0 = ldbs(buf, kb2, 0);
        u32x4 B1 = ldbs(buf, kb2, 1);
        accX[0] = MFMA16(a, lo2(B0), accX[0]);
        accX[1] = MFMA16(a, hi2(B0), accX[1]);
        accX[2] = MFMA16(a, lo2(B1), accX[2]);
        accX[3] = MFMA16(a, hi2(B1), accX[3]);
      }
    }
  }

  // Prefetch T chunk 0 (flies under epilogue + S2).
  stageA(task, 128, 0, 0); stageB(WtP, 0, 0);

  // ---- S1 epilogue: X1 -> x_lds ----
#pragma unroll
  for (int nt = 0; nt < 4; ++nt) {
    float bias = bs1[nt * 16 + p];
#pragma unroll
    for (int r = 0; r < 4; ++r)
      stx(4 * q + r, nt * 16 + p, fmaxf(accX[nt][r] + bias, 0.f));
  }

  // ---- S2: s = relu(X1 @ Ws2 + bs2), K=64 ----
  f32x4 accS[4] = {z4, z4, z4, z4};
#pragma unroll
  for (int kb = 0; kb < 4; ++kb) {
    h16x4 a = ldx4(p, kb * 16 + q * 4);
#pragma unroll
    for (int nt = 0; nt < 4; ++nt)
      accS[nt] = MFMA16(a, ldb(Ws2T, (nt * 16 + p) * 64 + kb * 16 + q * 4), accS[nt]);
  }
  float sf[4][4];
#pragma unroll
  for (int nt = 0; nt < 4; ++nt) {
    float bias = bs2[nt * 16 + p];
#pragma unroll
    for (int r = 0; r < 4; ++r) sf[nt][r] = fmaxf(accS[nt][r] + bias, 0.f);
  }
#pragma unroll
  for (int nt = 0; nt < 4; ++nt)
#pragma unroll
    for (int r = 0; r < 4; ++r) stx(4 * q + r, nt * 16 + p, sf[nt][r]);

  // ---- T: K=128 = 4 chunks; counted vmcnt, NO barriers ----
  f32x4 accT[4] = {z4, z4, z4, z4};
  {
    for (int c = 0; c < 4; ++c) {
      if (c + 1 < 4) {
        stageA(task, 128, (c + 1) * 32, (c + 1) & 1);
        stageB(WtP, c + 1, (c + 1) & 1);
        __builtin_amdgcn_sched_barrier(0);
        asm volatile("s_waitcnt vmcnt(6)" ::: "memory");
      } else {
        asm volatile("s_waitcnt vmcnt(0)" ::: "memory");
      }
      __builtin_amdgcn_sched_barrier(0);
      const int buf = c & 1;
#pragma unroll
      for (int kb2 = 0; kb2 < 2; ++kb2) {
        h16x4 a = cvtA(lda_(buf, kb2));
        u32x4 B0 = ldbs(buf, kb2, 0);
        u32x4 B1 = ldbs(buf, kb2, 1);
        accT[0] = MFMA16(a, lo2(B0), accT[0]);
        accT[1] = MFMA16(a, hi2(B0), accT[1]);
        accT[2] = MFMA16(a, lo2(B1), accT[2]);
        accT[3] = MFMA16(a, hi2(B1), accT[3]);
      }
    }
  }
  float r0f[4][4];
#pragma unroll
  for (int nt = 0; nt < 4; ++nt) {
    float bias = bt[nt * 16 + p];
#pragma unroll
    for (int r = 0; r < 4; ++r)
      r0f[nt][r] = sf[nt][r] * fmaxf(accT[nt][r] + bias, 0.f);
  }

  // ---- We0: m[j] = relu(s @ We0[j] + be0[j]), K=64 (x holds s) ----
  float mfr[4][2][4];
#pragma unroll
  for (int n = 0; n < 4; ++n) {
    f32x4 acc[2] = {z4, z4};
#pragma unroll
    for (int kb = 0; kb < 4; ++kb) {
      h16x4 a = ldx4(p, kb * 16 + q * 4);
#pragma unroll
      for (int nt = 0; nt < 2; ++nt)
        acc[nt] = MFMA16(a, ldb(We0T, (n * 32 + nt * 16 + p) * 64 + kb * 16 + q * 4), acc[nt]);
    }
#pragma unroll
    for (int nt = 0; nt < 2; ++nt) {
      float bias = be0[n * 32 + nt * 16 + p];
#pragma unroll
      for (int r = 0; r < 4; ++r) mfr[n][nt][r] = fmaxf(acc[nt][r] + bias, 0.f);
    }
  }

  // r0 -> x_lds
#pragma unroll
  for (int nt = 0; nt < 4; ++nt)
#pragma unroll
    for (int r = 0; r < 4; ++r) stx(4 * q + r, nt * 16 + p, r0f[nt][r]);

  // ---- A0: softmax over groups of 4 of (r0 @ Wa0 + ba0) ----
  f32x4 accA = z4;
#pragma unroll
  for (int kb = 0; kb < 4; ++kb)
    accA = MFMA16(ldx4(p, kb * 16 + q * 4), ldb(Wa0T, p * 64 + kb * 16 + q * 4), accA);
  float a0v[4];
  {
    float bias = ba0[p];
#pragma unroll
    for (int r = 0; r < 4; ++r) {
      float v = accA[r] + bias;
      float mx = fmaxf(v, __shfl_xor(v, 1));
      mx = fmaxf(mx, __shfl_xor(mx, 2));
      float e = __expf(v - mx);
      float ssum = e + __shfl_xor(e, 1);
      ssum += __shfl_xor(ssum, 2);
      a0v[r] = e / ssum;
    }
  }
#pragma unroll
  for (int r = 0; r < 4; ++r)
    *(short*)(a_lds + (4 * q + r) * 48 + p * 2) = h_bits(a0v[r]);

  // ---- combine 1: broadcast-read a0 rows ----
  float pv[4][2][4];
#pragma unroll
  for (int r = 0; r < 4; ++r) {
    h16x8 alo = *(const h16x8*)(a_lds + (4 * q + r) * 48);
    h16x8 ahi = *(const h16x8*)(a_lds + (4 * q + r) * 48 + 16);
    float av[16];
#pragma unroll
    for (int e = 0; e < 8; ++e) { av[e] = (float)alo[e]; av[8 + e] = (float)ahi[e]; }
#pragma unroll
    for (int i = 0; i < 4; ++i) {
      float s0 = 0.f, s1 = 0.f;
#pragma unroll
      for (int j = 0; j < 4; ++j) {
        s0 += av[4 * i + j] * mfr[j][0][r];
        s1 += av[4 * i + j] * mfr[j][1][r];
      }
      pv[i][0][r] = s0; pv[i][1][r] = s1;
    }
  }

  // ---- Wc0: r = relu((a0 @ Wc0 + bc0) * r0), K=16 ----
  f32x4 accC[4] = {z4, z4, z4, z4};
  {
    h16x4 a = *(const h16x4*)(a_lds + p * 48 + q * 8);
#pragma unroll
    for (int nt = 0; nt < 4; ++nt)
      accC[nt] = MFMA16(a, ldb(Wc0T, (nt * 16 + p) * 16 + q * 4), accC[nt]);
  }
  float rf[4][4];
#pragma unroll
  for (int nt = 0; nt < 4; ++nt) {
    float bias = bc0[nt * 16 + p];
#pragma unroll
    for (int r = 0; r < 4; ++r)
      rf[nt][r] = fmaxf((accC[nt][r] + bias) * r0f[nt][r], 0.f);
  }
#pragma unroll
  for (int nt = 0; nt < 4; ++nt)
#pragma unroll
    for (int r = 0; r < 4; ++r) stx(4 * q + r, nt * 16 + p, rf[nt][r]);

  // ---- A1: softmax(r @ Wa1 + ba1) ----
  f32x4 accA1 = z4;
#pragma unroll
  for (int kb = 0; kb < 4; ++kb)
    accA1 = MFMA16(ldx4(p, kb * 16 + q * 4), ldb(Wa1T, p * 64 + kb * 16 + q * 4), accA1);
  float a1v[4];
  {
    float bias = ba1[p];
#pragma unroll
    for (int r = 0; r < 4; ++r) {
      float v = accA1[r] + bias;
      float mx = fmaxf(v, __shfl_xor(v, 1));
      mx = fmaxf(mx, __shfl_xor(mx, 2));
      float e = __expf(v - mx);
      float ssum = e + __shfl_xor(e, 1);
      ssum += __shfl_xor(ssum, 2);
      a1v[r] = e / ssum;
    }
  }

  // ---- E1: pv -> pm_lds (overlays dead ring, v16-verified) ----
#pragma unroll
  for (int i = 0; i < 4; ++i)
#pragma unroll
    for (int nt = 0; nt < 2; ++nt)
#pragma unroll
      for (int r = 0; r < 4; ++r)
        *(short*)(pm_lds + (i * 16 + 4 * q + r) * 80 + (nt * 16 + p) * 2) = h_bits(pv[i][nt][r]);

  float m1f[4][2][4];
#pragma unroll
  for (int n = 0; n < 4; ++n) {
    f32x4 acc[2] = {z4, z4};
#pragma unroll
    for (int kb = 0; kb < 2; ++kb) {
      h16x4 a = *(const h16x4*)(pm_lds + (n * 16 + p) * 80 + kb * 32 + q * 8);
#pragma unroll
      for (int nt = 0; nt < 2; ++nt)
        acc[nt] = MFMA16(a, ldb(We1T, (n * 32 + nt * 16 + p) * 32 + kb * 16 + q * 4), acc[nt]);
    }
#pragma unroll
    for (int nt = 0; nt < 2; ++nt) {
      float bias = be1[n * 32 + nt * 16 + p];
#pragma unroll
      for (int r = 0; r < 4; ++r) m1f[n][nt][r] = fmaxf(acc[nt][r] + bias, 0.f);
    }
  }

  // ---- combine 2: shfl broadcast of a1 ----
  float pv2[4][2][4];
#pragma unroll
  for (int r = 0; r < 4; ++r) {
    float av[16];
#pragma unroll
    for (int cc = 0; cc < 16; ++cc)
      av[cc] = __shfl(a1v[r], (lane & 48) | cc);
#pragma unroll
    for (int i = 0; i < 4; ++i) {
      float s0 = 0.f, s1 = 0.f;
#pragma unroll
      for (int j = 0; j < 4; ++j) {
        s0 += av[4 * i + j] * m1f[j][0][r];
        s1 += av[4 * i + j] * m1f[j][1][r];
      }
      pv2[i][0][r] = s0; pv2[i][1][r] = s1;
    }
  }

  // ---- E2: pv2 -> pm_lds; sum over n; store f32 ----
#pragma unroll
  for (int i = 0; i < 4; ++i)
#pragma unroll
    for (int nt = 0; nt < 2; ++nt)
#pragma unroll
      for (int r = 0; r < 4; ++r)
        *(short*)(pm_lds + (i * 16 + 4 * q + r) * 80 + (nt * 16 + p) * 2) = h_bits(pv2[i][nt][r]);

  float of[2][4] = {{0.f, 0.f, 0.f, 0.f}, {0.f, 0.f, 0.f, 0.f}};
#pragma unroll
  for (int n = 0; n < 4; ++n) {
    f32x4 acc[2] = {z4, z4};
#pragma unroll
    for (int kb = 0; kb < 2; ++kb) {
      h16x4 a = *(const h16x4*)(pm_lds + (n * 16 + p) * 80 + kb * 32 + q * 8);
#pragma unroll
      for (int nt = 0; nt < 2; ++nt)
        acc[nt] = MFMA16(a, ldb(We2T, (n * 32 + nt * 16 + p) * 32 + kb * 16 + q * 4), acc[nt]);
    }
#pragma unroll
    for (int nt = 0; nt < 2; ++nt) {
      float bias = be2[n * 32 + nt * 16 + p];
#pragma unroll
      for (int r = 0; r < 4; ++r) of[nt][r] += fmaxf(acc[nt][r] + bias, 0.f);
    }
  }
#pragma unroll
  for (int nt = 0; nt < 2; ++nt)
#pragma unroll
    for (int r = 0; r < 4; ++r) {
      int grow = rowblk + 4 * q + r;
      out[(size_t)grow * 32 + nt * 16 + p] = of[nt][r];
    }
}

extern "C" void kernel_launch(void* const* d_in, const int* in_sizes, int n_in,
                              void* d_out, int out_size, void* d_ws, size_t ws_size,
                              hipStream_t stream) {
  (void)in_sizes; (void)n_in; (void)out_size; (void)ws_size;
  const float* obs  = (const float*)d_in[0];
  const float* task = (const float*)d_in[1];
  const float* Ws1 = (const float*)d_in[2];  const float* bs1 = (const float*)d_in[3];
  const float* Ws2 = (const float*)d_in[4];  const float* bs2 = (const float*)d_in[5];
  const float* Wt  = (const float*)d_in[6];  const float* bt  = (const float*)d_in[7];
  const float* Wa0 = (const float*)d_in[8];  const float* ba0 = (const float*)d_in[9];
  const float* Wa1 = (const float*)d_in[10]; const float* ba1 = (const float*)d_in[11];
  const float* Wc0 = (const float*)d_in[12]; const float* bc0 = (const float*)d_in[13];
  // d_in[14]=Wc1, d_in[15]=bc1: dead code in the reference (result unused)
  const float* We0 = (const float*)d_in[16]; const float* be0 = (const float*)d_in[17];
  const float* We1 = (const float*)d_in[18]; const float* be1 = (const float*)d_in[19];
  const float* We2 = (const float*)d_in[20]; const float* be2 = (const float*)d_in[21];

  short* wsh   = (short*)d_ws;
  float* biasf = (float*)((char*)d_ws + 129040);

  sm_convert_v19<<<dim3(255), dim3(256), 0, stream>>>(
      Ws1, Ws2, Wt, Wa0, Wa1, Wc0, We0, We1, We2,
      bs1, bs2, bt, ba0, ba1, bc0, be0, be1, be2,
      wsh, biasf);
  sm_fused_v19<<<dim3(2048), dim3(128), 0, stream>>>(
      obs, task, wsh, biasf, (float*)d_out);
}

// Round 20
// 67.518 us; speedup vs baseline: 1.1999x; 1.1999x over previous
//
#include <hip/hip_runtime.h>
#include <hip/hip_bf16.h>

// SoftModule fused forward, MI355X gfx950 — FINAL (= v13, verified best).
// SINGLE-WAVE workgroups end-to-end: 4096 WGs x 64 threads, 16 rows/wave,
// ZERO barriers (all LDS wave-private, all vmcnt waits wave-local).
// S1/T staging: A source-XOR-swizzled 2KB chunks + B packed 4KB chunks via
// global_load_lds, vmcnt(6)-counted DMA-only FIFO, depth-1 double buffer.
// Mid-phases: broadcast-read combine1, shfl combine2. 67.7us, absmax 0.03125.
//
// Session findings (rounds 4-19): all staging structures converge to
// ~900 GB/s == (~7 resident waves/CU) x (~2 outstanding 1KB LDS-DMAs/wave)
// x ~400ns HBM latency. Occupancy (v16/v19), chain-count (v17), prefetch
// depth (v12/v18), and register pipelines (v6) are all measured-dead levers;
// this barrier-free single-wave form is the structure's floor.

using f32x4 = __attribute__((ext_vector_type(4))) float;
using h16x4 = __attribute__((ext_vector_type(4))) _Float16;
using h16x8 = __attribute__((ext_vector_type(8))) _Float16;
using u32x4 = __attribute__((ext_vector_type(4))) unsigned int;
using u32x2 = __attribute__((ext_vector_type(2))) unsigned int;

#define MFMA16(a, b, c) __builtin_amdgcn_mfma_f32_16x16x16f16((a), (b), (c), 0, 0, 0)

__device__ __forceinline__ short h_bits(float f) {
  _Float16 h = (_Float16)f;
  return __builtin_bit_cast(short, h);
}

__device__ __forceinline__ void dma16(const void* g, char* l) {
  __builtin_amdgcn_global_load_lds(
      (const __attribute__((address_space(1))) unsigned int*)g,
      (__attribute__((address_space(3))) unsigned int*)l, 16, 0, 0);
}

// ---------------- weight convert (v9, verified) -----------------------------
__global__ void sm_convert_vf(
    const float* __restrict__ Ws1, const float* __restrict__ Ws2, const float* __restrict__ Wt,
    const float* __restrict__ Wa0, const float* __restrict__ Wa1, const float* __restrict__ Wc0,
    const float* __restrict__ We0, const float* __restrict__ We1, const float* __restrict__ We2,
    const float* __restrict__ bs1, const float* __restrict__ bs2, const float* __restrict__ bt,
    const float* __restrict__ ba0, const float* __restrict__ ba1, const float* __restrict__ bc0,
    const float* __restrict__ be0, const float* __restrict__ be1, const float* __restrict__ be2,
    short* __restrict__ wsh, float* __restrict__ biasf) {
  int d = blockIdx.x * 256 + threadIdx.x;
  if (d < 64512) {
    float v;
    if (d < 32768) {             // Bp1 (v9 bijection)
      int kk   = d & 3;
      int ntip = (d >> 2) & 1;
      int p    = (d >> 3) & 15;
      int q    = (d >> 7) & 3;
      int pair = (d >> 9) & 1;
      int kb2  = (d >> 10) & 1;
      int c    = d >> 11;
      int k = c * 32 + kb2 * 16 + q * 4 + kk;
      int o = pair * 32 + ntip * 16 + p;
      v = Ws1[k * 64 + o];
    }
    else if (d < 36864) { int r = d - 32768, o = r >> 6, k = r & 63;   v = Ws2[k * 64 + o]; }
    else if (d < 45056) {        // WtP
      int r = d - 36864;
      int kk   = r & 3;
      int ntip = (r >> 2) & 1;
      int p    = (r >> 3) & 15;
      int q    = (r >> 7) & 3;
      int pair = (r >> 9) & 1;
      int kb2  = (r >> 10) & 1;
      int c    = r >> 11;
      int k = c * 32 + kb2 * 16 + q * 4 + kk;
      int o = pair * 32 + ntip * 16 + p;
      v = Wt[k * 64 + o];
    }
    else if (d < 46080) { int r = d - 45056, o = r >> 6, k = r & 63;   v = Wa0[k * 16 + o]; }
    else if (d < 47104) { int r = d - 46080, o = r >> 6, k = r & 63;   v = Wa1[k * 16 + o]; }
    else if (d < 48128) { int r = d - 47104, o = r >> 4, k = r & 15;   v = Wc0[k * 64 + o]; }
    else if (d < 56320) { int r = d - 48128, n = r >> 11, o = (r >> 6) & 31, i = r & 63; v = We0[n * 2048 + i * 32 + o]; }
    else if (d < 60416) { int r = d - 56320, n = r >> 10, o = (r >> 5) & 31, i = r & 31; v = We1[n * 1024 + i * 32 + o]; }
    else                { int r = d - 60416, n = r >> 10, o = (r >> 5) & 31, i = r & 31; v = We2[n * 1024 + i * 32 + o]; }
    wsh[d] = h_bits(v);
  } else if (d < 65184) {
    int r = d - 64512;
    float v;
    if      (r < 64)  v = bs1[r];
    else if (r < 128) v = bs2[r - 64];
    else if (r < 192) v = bt[r - 128];
    else if (r < 208) v = ba0[r - 192];
    else if (r < 224) v = ba1[r - 208];
    else if (r < 288) v = bc0[r - 224];
    else if (r < 416) v = be0[r - 288];
    else if (r < 544) v = be1[r - 416];
    else              v = be2[r - 544];
    biasf[r] = v;
  }
}

// ---------------- fused forward: single-wave WGs ----------------------------
__global__ __launch_bounds__(64) void sm_fused_vf(
    const float* __restrict__ obs, const float* __restrict__ task,
    const short* __restrict__ wsh, const float* __restrict__ biasf,
    float* __restrict__ out) {
  const int lane = threadIdx.x & 63;
  const int q    = lane >> 4;
  const int p    = lane & 15;
  const int rowblk = blockIdx.x * 16;

  // Wave-private LDS, no overlays, no barriers:
  // x[16][136] @0 (2176) | a[16][48] @2176 (768) | pm[4][16][80] @2944 (5120)
  // ring[2][6144: A 2048 + B 4096] @8064 (12288). Total 20352.
  __shared__ __align__(16) char lds[20352];
  char* x_lds  = lds;
  char* a_lds  = lds + 2176;
  char* pm_lds = lds + 2944;
  char* ring   = lds + 8064;

  const short* Bp1  = wsh;
  const short* Ws2T = wsh + 32768;
  const short* WtP  = wsh + 36864;
  const short* Wa0T = wsh + 45056;
  const short* Wa1T = wsh + 46080;
  const short* Wc0T = wsh + 47104;
  const short* We0T = wsh + 48128;
  const short* We1T = wsh + 56320;
  const short* We2T = wsh + 60416;
  const float* bs1 = biasf;        const float* bs2 = biasf + 64;
  const float* bt  = biasf + 128;  const float* ba0 = biasf + 192;
  const float* ba1 = biasf + 208;  const float* bc0 = biasf + 224;
  const float* be0 = biasf + 288;  const float* be1 = biasf + 416;
  const float* be2 = biasf + 544;

  const f32x4 z4 = {0.f, 0.f, 0.f, 0.f};

  auto stx  = [&](int row, int col, float v) { *(short*)(x_lds + row * 136 + col * 2) = h_bits(v); };
  auto ldx4 = [&](int row, int k0) -> h16x4 { return *(const h16x4*)(x_lds + row * 136 + k0 * 2); };
  auto ldb  = [&](const short* W, int off) -> h16x4 { return *(const h16x4*)(W + off); };
  auto cvtA = [&](const u32x4& u) -> h16x4 {
    float4 v = __builtin_bit_cast(float4, u);
    h16x4 a;
    a[0] = (_Float16)v.x; a[1] = (_Float16)v.y;
    a[2] = (_Float16)v.z; a[3] = (_Float16)v.w;
    return a;
  };
  auto lo2 = [&](const u32x4& u) -> h16x4 { return __builtin_bit_cast(h16x4, (u32x2){u[0], u[1]}); };
  auto hi2 = [&](const u32x4& u) -> h16x4 { return __builtin_bit_cast(h16x4, (u32x2){u[2], u[3]}); };

  // Stage A: 16 rows x 32 f32 (2KB), source XOR swizzle, linear LDS; 2 dma.
  auto stageA = [&](const float* base, int rowlen, int k0, int buf) {
#pragma unroll
    for (int j = 0; j < 2; ++j) {
      int f = j * 64 + lane;
      int row = f >> 3;
      int cl = (f & 7) ^ (row & 7);
      dma16(base + (size_t)(rowblk + row) * rowlen + k0 + cl * 4,
            ring + buf * 6144 + j * 1024);
    }
  };
  // Stage B: linear 4KB identity copy of packed chunk; 4 dma.
  auto stageB = [&](const short* bsrc, int c, int buf) {
#pragma unroll
    for (int j = 0; j < 4; ++j)
      dma16((const char*)bsrc + c * 4096 + (j * 64 + lane) * 16,
            ring + buf * 6144 + 2048 + j * 1024);
  };
  auto lda_ = [&](int buf, int kb2) -> u32x4 {
    return *(const u32x4*)(ring + buf * 6144 + p * 128 +
                           (((kb2 * 4 + q) ^ (p & 7)) * 16));
  };
  auto ldbs = [&](int buf, int kb2, int pair) -> u32x4 {
    return *(const u32x4*)(ring + buf * 6144 + 2048 + kb2 * 2048 + pair * 1024 + lane * 16);
  };

  // ---- S1: K=512 = 16 chunks of 32; counted vmcnt, NO barriers ----
  f32x4 accX[4] = {z4, z4, z4, z4};
  {
    stageA(obs, 512, 0, 0); stageB(Bp1, 0, 0);      // 6 DMAs, chunk 0
    for (int c = 0; c < 16; ++c) {
      if (c + 1 < 16) {
        stageA(obs, 512, (c + 1) * 32, (c + 1) & 1);
        stageB(Bp1, c + 1, (c + 1) & 1);
        __builtin_amdgcn_sched_barrier(0);
        asm volatile("s_waitcnt vmcnt(6)" ::: "memory");  // retires chunk c, keeps c+1
      } else {
        asm volatile("s_waitcnt vmcnt(0)" ::: "memory");
      }
      __builtin_amdgcn_sched_barrier(0);
      const int buf = c & 1;
#pragma unroll
      for (int kb2 = 0; kb2 < 2; ++kb2) {
        h16x4 a = cvtA(lda_(buf, kb2));
        u32x4 B0 = ldbs(buf, kb2, 0);
        u32x4 B1 = ldbs(buf, kb2, 1);
        accX[0] = MFMA16(a, lo2(B0), accX[0]);
        accX[1] = MFMA16(a, hi2(B0), accX[1]);
        accX[2] = MFMA16(a, lo2(B1), accX[2]);
        accX[3] = MFMA16(a, hi2(B1), accX[3]);
      }
    }
  }

  // Prefetch T chunk 0 (flies under epilogue + S2).
  stageA(task, 128, 0, 0); stageB(WtP, 0, 0);

  // ---- S1 epilogue: X1 -> x_lds ----
#pragma unroll
  for (int nt = 0; nt < 4; ++nt) {
    float bias = bs1[nt * 16 + p];
#pragma unroll
    for (int r = 0; r < 4; ++r)
      stx(4 * q + r, nt * 16 + p, fmaxf(accX[nt][r] + bias, 0.f));
  }

  // ---- S2: s = relu(X1 @ Ws2 + bs2), K=64 ----
  f32x4 accS[4] = {z4, z4, z4, z4};
#pragma unroll
  for (int kb = 0; kb < 4; ++kb) {
    h16x4 a = ldx4(p, kb * 16 + q * 4);
#pragma unroll
    for (int nt = 0; nt < 4; ++nt)
      accS[nt] = MFMA16(a, ldb(Ws2T, (nt * 16 + p) * 64 + kb * 16 + q * 4), accS[nt]);
  }
  float sf[4][4];
#pragma unroll
  for (int nt = 0; nt < 4; ++nt) {
    float bias = bs2[nt * 16 + p];
#pragma unroll
    for (int r = 0; r < 4; ++r) sf[nt][r] = fmaxf(accS[nt][r] + bias, 0.f);
  }
#pragma unroll
  for (int nt = 0; nt < 4; ++nt)
#pragma unroll
    for (int r = 0; r < 4; ++r) stx(4 * q + r, nt * 16 + p, sf[nt][r]);

  // ---- T: K=128 = 4 chunks; counted vmcnt, NO barriers ----
  f32x4 accT[4] = {z4, z4, z4, z4};
  {
    for (int c = 0; c < 4; ++c) {
      if (c + 1 < 4) {
        stageA(task, 128, (c + 1) * 32, (c + 1) & 1);
        stageB(WtP, c + 1, (c + 1) & 1);
        __builtin_amdgcn_sched_barrier(0);
        asm volatile("s_waitcnt vmcnt(6)" ::: "memory");
      } else {
        asm volatile("s_waitcnt vmcnt(0)" ::: "memory");
      }
      __builtin_amdgcn_sched_barrier(0);
      const int buf = c & 1;
#pragma unroll
      for (int kb2 = 0; kb2 < 2; ++kb2) {
        h16x4 a = cvtA(lda_(buf, kb2));
        u32x4 B0 = ldbs(buf, kb2, 0);
        u32x4 B1 = ldbs(buf, kb2, 1);
        accT[0] = MFMA16(a, lo2(B0), accT[0]);
        accT[1] = MFMA16(a, hi2(B0), accT[1]);
        accT[2] = MFMA16(a, lo2(B1), accT[2]);
        accT[3] = MFMA16(a, hi2(B1), accT[3]);
      }
    }
  }
  float r0f[4][4];
#pragma unroll
  for (int nt = 0; nt < 4; ++nt) {
    float bias = bt[nt * 16 + p];
#pragma unroll
    for (int r = 0; r < 4; ++r)
      r0f[nt][r] = sf[nt][r] * fmaxf(accT[nt][r] + bias, 0.f);
  }

  // ---- We0: m[j] = relu(s @ We0[j] + be0[j]), K=64 (x holds s) ----
  float mfr[4][2][4];
#pragma unroll
  for (int n = 0; n < 4; ++n) {
    f32x4 acc[2] = {z4, z4};
#pragma unroll
    for (int kb = 0; kb < 4; ++kb) {
      h16x4 a = ldx4(p, kb * 16 + q * 4);
#pragma unroll
      for (int nt = 0; nt < 2; ++nt)
        acc[nt] = MFMA16(a, ldb(We0T, (n * 32 + nt * 16 + p) * 64 + kb * 16 + q * 4), acc[nt]);
    }
#pragma unroll
    for (int nt = 0; nt < 2; ++nt) {
      float bias = be0[n * 32 + nt * 16 + p];
#pragma unroll
      for (int r = 0; r < 4; ++r) mfr[n][nt][r] = fmaxf(acc[nt][r] + bias, 0.f);
    }
  }

  // r0 -> x_lds
#pragma unroll
  for (int nt = 0; nt < 4; ++nt)
#pragma unroll
    for (int r = 0; r < 4; ++r) stx(4 * q + r, nt * 16 + p, r0f[nt][r]);

  // ---- A0: softmax over groups of 4 of (r0 @ Wa0 + ba0) ----
  f32x4 accA = z4;
#pragma unroll
  for (int kb = 0; kb < 4; ++kb)
    accA = MFMA16(ldx4(p, kb * 16 + q * 4), ldb(Wa0T, p * 64 + kb * 16 + q * 4), accA);
  float a0v[4];
  {
    float bias = ba0[p];
#pragma unroll
    for (int r = 0; r < 4; ++r) {
      float v = accA[r] + bias;
      float mx = fmaxf(v, __shfl_xor(v, 1));
      mx = fmaxf(mx, __shfl_xor(mx, 2));
      float e = __expf(v - mx);
      float ssum = e + __shfl_xor(e, 1);
      ssum += __shfl_xor(ssum, 2);
      a0v[r] = e / ssum;
    }
  }
#pragma unroll
  for (int r = 0; r < 4; ++r)
    *(short*)(a_lds + (4 * q + r) * 48 + p * 2) = h_bits(a0v[r]);

  // ---- combine 1: broadcast-read a0 rows ----
  float pv[4][2][4];
#pragma unroll
  for (int r = 0; r < 4; ++r) {
    h16x8 alo = *(const h16x8*)(a_lds + (4 * q + r) * 48);
    h16x8 ahi = *(const h16x8*)(a_lds + (4 * q + r) * 48 + 16);
    float av[16];
#pragma unroll
    for (int e = 0; e < 8; ++e) { av[e] = (float)alo[e]; av[8 + e] = (float)ahi[e]; }
#pragma unroll
    for (int i = 0; i < 4; ++i) {
      float s0 = 0.f, s1 = 0.f;
#pragma unroll
      for (int j = 0; j < 4; ++j) {
        s0 += av[4 * i + j] * mfr[j][0][r];
        s1 += av[4 * i + j] * mfr[j][1][r];
      }
      pv[i][0][r] = s0; pv[i][1][r] = s1;
    }
  }

  // ---- Wc0: r = relu((a0 @ Wc0 + bc0) * r0), K=16 ----
  f32x4 accC[4] = {z4, z4, z4, z4};
  {
    h16x4 a = *(const h16x4*)(a_lds + p * 48 + q * 8);
#pragma unroll
    for (int nt = 0; nt < 4; ++nt)
      accC[nt] = MFMA16(a, ldb(Wc0T, (nt * 16 + p) * 16 + q * 4), accC[nt]);
  }
  float rf[4][4];
#pragma unroll
  for (int nt = 0; nt < 4; ++nt) {
    float bias = bc0[nt * 16 + p];
#pragma unroll
    for (int r = 0; r < 4; ++r)
      rf[nt][r] = fmaxf((accC[nt][r] + bias) * r0f[nt][r], 0.f);
  }
#pragma unroll
  for (int nt = 0; nt < 4; ++nt)
#pragma unroll
    for (int r = 0; r < 4; ++r) stx(4 * q + r, nt * 16 + p, rf[nt][r]);

  // ---- A1: softmax(r @ Wa1 + ba1) ----
  f32x4 accA1 = z4;
#pragma unroll
  for (int kb = 0; kb < 4; ++kb)
    accA1 = MFMA16(ldx4(p, kb * 16 + q * 4), ldb(Wa1T, p * 64 + kb * 16 + q * 4), accA1);
  float a1v[4];
  {
    float bias = ba1[p];
#pragma unroll
    for (int r = 0; r < 4; ++r) {
      float v = accA1[r] + bias;
      float mx = fmaxf(v, __shfl_xor(v, 1));
      mx = fmaxf(mx, __shfl_xor(mx, 2));
      float e = __expf(v - mx);
      float ssum = e + __shfl_xor(e, 1);
      ssum += __shfl_xor(ssum, 2);
      a1v[r] = e / ssum;
    }
  }

  // ---- E1: pv -> pm_lds; m1 = relu(prev1 @ We1 + be1), K=32 ----
#pragma unroll
  for (int i = 0; i < 4; ++i)
#pragma unroll
    for (int nt = 0; nt < 2; ++nt)
#pragma unroll
      for (int r = 0; r < 4; ++r)
        *(short*)(pm_lds + (i * 16 + 4 * q + r) * 80 + (nt * 16 + p) * 2) = h_bits(pv[i][nt][r]);

  float m1f[4][2][4];
#pragma unroll
  for (int n = 0; n < 4; ++n) {
    f32x4 acc[2] = {z4, z4};
#pragma unroll
    for (int kb = 0; kb < 2; ++kb) {
      h16x4 a = *(const h16x4*)(pm_lds + (n * 16 + p) * 80 + kb * 32 + q * 8);
#pragma unroll
      for (int nt = 0; nt < 2; ++nt)
        acc[nt] = MFMA16(a, ldb(We1T, (n * 32 + nt * 16 + p) * 32 + kb * 16 + q * 4), acc[nt]);
    }
#pragma unroll
    for (int nt = 0; nt < 2; ++nt) {
      float bias = be1[n * 32 + nt * 16 + p];
#pragma unroll
      for (int r = 0; r < 4; ++r) m1f[n][nt][r] = fmaxf(acc[nt][r] + bias, 0.f);
    }
  }

  // ---- combine 2: shfl broadcast of a1 ----
  float pv2[4][2][4];
#pragma unroll
  for (int r = 0; r < 4; ++r) {
    float av[16];
#pragma unroll
    for (int cc = 0; cc < 16; ++cc)
      av[cc] = __shfl(a1v[r], (lane & 48) | cc);
#pragma unroll
    for (int i = 0; i < 4; ++i) {
      float s0 = 0.f, s1 = 0.f;
#pragma unroll
      for (int j = 0; j < 4; ++j) {
        s0 += av[4 * i + j] * m1f[j][0][r];
        s1 += av[4 * i + j] * m1f[j][1][r];
      }
      pv2[i][0][r] = s0; pv2[i][1][r] = s1;
    }
  }

  // ---- E2: pv2 -> pm_lds; sum over n; store f32 ----
#pragma unroll
  for (int i = 0; i < 4; ++i)
#pragma unroll
    for (int nt = 0; nt < 2; ++nt)
#pragma unroll
      for (int r = 0; r < 4; ++r)
        *(short*)(pm_lds + (i * 16 + 4 * q + r) * 80 + (nt * 16 + p) * 2) = h_bits(pv2[i][nt][r]);

  float of[2][4] = {{0.f, 0.f, 0.f, 0.f}, {0.f, 0.f, 0.f, 0.f}};
#pragma unroll
  for (int n = 0; n < 4; ++n) {
    f32x4 acc[2] = {z4, z4};
#pragma unroll
    for (int kb = 0; kb < 2; ++kb) {
      h16x4 a = *(const h16x4*)(pm_lds + (n * 16 + p) * 80 + kb * 32 + q * 8);
#pragma unroll
      for (int nt = 0; nt < 2; ++nt)
        acc[nt] = MFMA16(a, ldb(We2T, (n * 32 + nt * 16 + p) * 32 + kb * 16 + q * 4), acc[nt]);
    }
#pragma unroll
    for (int nt = 0; nt < 2; ++nt) {
      float bias = be2[n * 32 + nt * 16 + p];
#pragma unroll
      for (int r = 0; r < 4; ++r) of[nt][r] += fmaxf(acc[nt][r] + bias, 0.f);
    }
  }
#pragma unroll
  for (int nt = 0; nt < 2; ++nt)
#pragma unroll
    for (int r = 0; r < 4; ++r) {
      int grow = rowblk + 4 * q + r;
      out[(size_t)grow * 32 + nt * 16 + p] = of[nt][r];
    }
}

extern "C" void kernel_launch(void* const* d_in, const int* in_sizes, int n_in,
                              void* d_out, int out_size, void* d_ws, size_t ws_size,
                              hipStream_t stream) {
  (void)in_sizes; (void)n_in; (void)out_size; (void)ws_size;
  const float* obs  = (const float*)d_in[0];
  const float* task = (const float*)d_in[1];
  const float* Ws1 = (const float*)d_in[2];  const float* bs1 = (const float*)d_in[3];
  const float* Ws2 = (const float*)d_in[4];  const float* bs2 = (const float*)d_in[5];
  const float* Wt  = (const float*)d_in[6];  const float* bt  = (const float*)d_in[7];
  const float* Wa0 = (const float*)d_in[8];  const float* ba0 = (const float*)d_in[9];
  const float* Wa1 = (const float*)d_in[10]; const float* ba1 = (const float*)d_in[11];
  const float* Wc0 = (const float*)d_in[12]; const float* bc0 = (const float*)d_in[13];
  // d_in[14]=Wc1, d_in[15]=bc1: dead code in the reference (result unused)
  const float* We0 = (const float*)d_in[16]; const float* be0 = (const float*)d_in[17];
  const float* We1 = (const float*)d_in[18]; const float* be1 = (const float*)d_in[19];
  const float* We2 = (const float*)d_in[20]; const float* be2 = (const float*)d_in[21];

  short* wsh   = (short*)d_ws;
  float* biasf = (float*)((char*)d_ws + 129040);

  sm_convert_vf<<<dim3(255), dim3(256), 0, stream>>>(
      Ws1, Ws2, Wt, Wa0, Wa1, Wc0, We0, We1, We2,
      bs1, bs2, bt, ba0, ba1, bc0, be0, be1, be2,
      wsh, biasf);
  sm_fused_vf<<<dim3(4096), dim3(64), 0, stream>>>(
      obs, task, wsh, biasf, (float*)d_out);
}